// Round 12
// baseline (57.513 us; speedup 1.0000x reference)
//
#include <hip/hip_runtime.h>
#include <math.h>

// Problem constants
#define Dq 512
#define Vq 50257
#define Kq 100
#define KP 112               // K padded to 7*16
#define NORM_TERM 10.8249051f    // log(50257)
#define LOGK 4.6051702f          // log(100)
#define NBLK 512             // 16384 positions / 32 per block
#define DT_STRIDE 3584       // nBT: KP*32 elems per d-chunk slab (7KB, non-pow2)
#define PSP (16416 * 32)     // inT: padded pos-slab stride (1.002MB, non-pow2)

typedef __attribute__((ext_vector_type(8))) short short8;
typedef __attribute__((ext_vector_type(4))) float floatx4;
typedef __attribute__((ext_vector_type(4))) unsigned short ushort4v;

__device__ __forceinline__ unsigned short f2bf(float f) {
    union { float f; unsigned u; } v; v.f = f;
    unsigned r = v.u + 0x7FFFu + ((v.u >> 16) & 1u);   // RNE
    return (unsigned short)(r >> 16);
}

__device__ __forceinline__ float dot4(floatx4 a, floatx4 b) {
    return a.x*b.x + a.y*b.y + a.z*b.z + a.w*b.w;
}

__device__ __forceinline__ float log_sigmoid(float x) {
    return fminf(x, 0.f) - __logf(1.f + __expf(-fabsf(x)));
}

// Combined prep:
//  blocks 0..111:    noise row k -> nBT chunk-major (as R8) + nAdj[k];
//                    block 0 also zeroes out[64] (atomics accumulate later).
//  blocks 112..2159: transpose 8 input rows each -> inT chunk-major bf16:
//                    element (pos,d) at inT[(d>>5)*PSP + pos*32 + (d&31)].
__global__ void prep(const float* __restrict__ emb_w,
                     const float* __restrict__ emb_b,
                     const float* __restrict__ lpn,
                     const int* __restrict__ ns,
                     const float* __restrict__ input,
                     unsigned short* __restrict__ nBT,
                     float* __restrict__ nAdj,
                     unsigned short* __restrict__ inT,
                     float* __restrict__ out) {
    int bid = blockIdx.x;
    int t   = threadIdx.x;      // 0..127; dt = t>>3, sub = t&7
    if (bid < KP) {
        int k = bid;
        size_t off = (size_t)(t >> 3) * DT_STRIDE + k * 32 + (t & 7) * 4;
        if (k < Kq) {
            int row = ns[k];
            floatx4 v = ((const floatx4*)(emb_w + (size_t)row * Dq))[t];
            ushort4v o;
            o.x = f2bf(v.x); o.y = f2bf(v.y); o.z = f2bf(v.z); o.w = f2bf(v.w);
            *(ushort4v*)(nBT + off) = o;
            if (t == 0) nAdj[k] = emb_b[row] - NORM_TERM - lpn[row] - LOGK;
        } else {
            ushort4v z; z.x = 0; z.y = 0; z.z = 0; z.w = 0;
            *(ushort4v*)(nBT + off) = z;
            if (t == 0) nAdj[k] = 0.f;
        }
        if (bid == 0 && t < 64) out[t] = 0.f;
    } else {
        int r0 = (bid - KP) * 8;
#pragma unroll
        for (int j = 0; j < 8; ++j) {
            int row = r0 + j;
            floatx4 v = ((const floatx4*)(input + (size_t)row * Dq))[t];
            ushort4v o;
            o.x = f2bf(v.x); o.y = f2bf(v.y); o.z = f2bf(v.z); o.w = f2bf(v.w);
            *(ushort4v*)(inT + (size_t)(t >> 3) * PSP + (size_t)row * 32 + (t & 7) * 4) = o;
        }
    }
}

// Block = 8 waves = 32 positions. ZERO LDS, ZERO barriers: waves fully
// independent. Wave w: (1) fp32 target dots for positions 4w..4w+3
// (full-row 2KB bursts, shfl-reduced, epilogue on lane 0); (2) if w<7,
// noise k-tile w vs both 16-row M-tiles with A-fragments read DIRECTLY
// from transposed inT (contiguous 1KB bursts; no staging). Slab strides
// non-pow2 -> L2-channel rotation (R8 lesson). Per-wave result atomicAdd
// into out[batch] (order noise ~1e-4 << threshold).
__global__ __launch_bounds__(512, 4) void nce_main(
    const float* __restrict__ input,     // [16384][512] fp32
    const float* __restrict__ emb_w,     // [V][512]
    const float* __restrict__ emb_b,     // [V]
    const float* __restrict__ lpn,       // [V]
    const int* __restrict__ target,      // [16384]
    const unsigned short* __restrict__ nBT,  // noise, chunk-major bf16
    const float* __restrict__ nAdj,          // [112]
    const unsigned short* __restrict__ inT,  // input, chunk-major bf16
    float* __restrict__ out)                 // [64] accumulated
{
    int tid  = threadIdx.x;
    int lane = tid & 63;
    int w    = tid >> 6;            // 0..7
    int pos0 = (int)blockIdx.x * 32;
    int r16  = lane & 15;
    int g4   = lane >> 4;

    float contrib = 0.f;

    // ---- Target dots: positions pos0+4w .. +3 (fp32, full-row bursts) ----
#pragma unroll
    for (int j = 0; j < 4; ++j) {
        int pos = pos0 + 4 * w + j;
        int tg  = target[pos];                       // wave-uniform
        const float* src  = input + (size_t)pos * Dq + lane * 8;
        const float* tsrc = emb_w + (size_t)tg  * Dq + lane * 8;
        floatx4 x0 = *(const floatx4*)(src);
        floatx4 x1 = *(const floatx4*)(src + 4);
        floatx4 t0 = *(const floatx4*)(tsrc);
        floatx4 t1 = *(const floatx4*)(tsrc + 4);
        float s = dot4(x0, t0) + dot4(x1, t1);
#pragma unroll
        for (int off = 32; off >= 1; off >>= 1)
            s += __shfl_xor(s, off);
        if (lane == 0)
            contrib += log_sigmoid(s + emb_b[tg] - NORM_TERM - lpn[tg] - LOGK);
    }

    // ---- Noise k-tile w vs both M-tiles: direct global A-bursts ----
    if (w < 7) {
        const unsigned short* pa = inT + (size_t)(pos0 + r16) * 32 + g4 * 8;
        const unsigned short* pb = nBT + (size_t)w * 512 + r16 * 32 + g4 * 8;
        floatx4 acc0 = {0.f, 0.f, 0.f, 0.f};
        floatx4 acc1 = {0.f, 0.f, 0.f, 0.f};
#pragma unroll
        for (int dt = 0; dt < 16; ++dt) {
            short8 a0 = *(const short8*)(pa + (size_t)dt * PSP);
            short8 a1 = *(const short8*)(pa + (size_t)dt * PSP + 16 * 32);
            short8 b  = *(const short8*)(pb + (size_t)dt * DT_STRIDE);
            acc0 = __builtin_amdgcn_mfma_f32_16x16x32_bf16(a0, b, acc0, 0, 0, 0);
            acc1 = __builtin_amdgcn_mfma_f32_16x16x32_bf16(a1, b, acc1, 0, 0, 0);
        }
        int k = w * 16 + r16;
        if (k < Kq) {
            float adj = nAdj[k];
#pragma unroll
            for (int r = 0; r < 4; ++r) {
                contrib += log_sigmoid(-(acc0[r] + adj));
                contrib += log_sigmoid(-(acc1[r] + adj));
            }
        }
    }

#pragma unroll
    for (int off = 32; off >= 1; off >>= 1)
        contrib += __shfl_xor(contrib, off);
    if (lane == 0)
        atomicAdd(&out[blockIdx.x >> 3], contrib);   // batch = pos0/256
}

extern "C" void kernel_launch(void* const* d_in, const int* in_sizes, int n_in,
                              void* d_out, int out_size, void* d_ws, size_t ws_size,
                              hipStream_t stream) {
    const float* input = (const float*)d_in[0];
    const float* emb_w = (const float*)d_in[1];
    const float* emb_b = (const float*)d_in[2];
    const float* lpn   = (const float*)d_in[3];
    const int*   tgt   = (const int*)d_in[4];
    const int*   ns    = (const int*)d_in[5];
    float* out = (float*)d_out;

    // ws layout: [0,114688) nBT; [114688,115200) nAdj(+pad);
    // [115200, 115200+16.8MB) inT (padded chunk-major bf16).
    unsigned short* nBT = (unsigned short*)d_ws;
    float* nAdj         = (float*)((char*)d_ws + (size_t)KP * Dq * 2);
    unsigned short* inT = (unsigned short*)((char*)d_ws + (size_t)KP * Dq * 2 + 512);

    prep<<<KP + 2048, 128, 0, stream>>>(emb_w, emb_b, lpn, ns, input,
                                        nBT, nAdj, inT, out);
    nce_main<<<NBLK, 512, 0, stream>>>(input, emb_w, emb_b, lpn, tgt,
                                       nBT, nAdj, inT, out);
}

// Round 13
// 27.226 us; speedup vs baseline: 2.1124x; 2.1124x over previous
//
#include <hip/hip_runtime.h>
#include <math.h>

// Problem constants
#define Dq 512
#define Vq 50257
#define Kq 100
#define KP 112              // K padded to 7*16
#define NORM_TERM 10.8249051f   // log(50257)
#define LOGK 4.6051702f         // log(100)
#define NBLK 512            // 16384 positions / 32 per block
#define DT_STRIDE 3584      // nBT: KP*32 elems per d-chunk slab (7KB, non-pow2)

typedef __attribute__((ext_vector_type(8))) short short8;
typedef __attribute__((ext_vector_type(4))) float floatx4;
typedef __attribute__((ext_vector_type(4))) unsigned short ushort4v;
typedef __attribute__((ext_vector_type(8))) unsigned short ushort8v;

__device__ __forceinline__ unsigned short f2bf(float f) {
    union { float f; unsigned u; } v; v.f = f;
    unsigned r = v.u + 0x7FFFu + ((v.u >> 16) & 1u);   // RNE
    return (unsigned short)(r >> 16);
}

__device__ __forceinline__ short8 cvt8(floatx4 a, floatx4 b) {
    short8 o;
    o[0] = (short)f2bf(a.x); o[1] = (short)f2bf(a.y);
    o[2] = (short)f2bf(a.z); o[3] = (short)f2bf(a.w);
    o[4] = (short)f2bf(b.x); o[5] = (short)f2bf(b.y);
    o[6] = (short)f2bf(b.z); o[7] = (short)f2bf(b.w);
    return o;
}

__device__ __forceinline__ float dot4(floatx4 a, floatx4 b) {
    return a.x*b.x + a.y*b.y + a.z*b.z + a.w*b.w;
}

__device__ __forceinline__ float log_sigmoid(float x) {
    return fminf(x, 0.f) - __logf(1.f + __expf(-fabsf(x)));
}

// Gather + convert noise rows to bf16, TRANSPOSED chunk-major layout
// (R8 win): element (k, d) at nBT[(d>>5)*DT_STRIDE + k*32 + (d&31)].
// A wave reading 16 k-rows x 4 chunks of one dt hits ONE contiguous 1KB
// block. Block 0 also zeroes out[64] for nce_main's atomic accumulation.
__global__ void prep_noise(const float* __restrict__ emb_w,
                           const float* __restrict__ emb_b,
                           const float* __restrict__ lpn,
                           const int* __restrict__ ns,
                           unsigned short* __restrict__ nBT,
                           float* __restrict__ nAdj,
                           float* __restrict__ out) {
    int k = blockIdx.x;     // 0..111
    int t = threadIdx.x;    // 0..127; d = t*4 .. t*4+3
    size_t off = (size_t)(t >> 3) * DT_STRIDE + k * 32 + (t & 7) * 4;
    if (k < Kq) {
        int row = ns[k];
        floatx4 v = ((const floatx4*)(emb_w + (size_t)row * Dq))[t];
        ushort4v o;
        o.x = f2bf(v.x); o.y = f2bf(v.y); o.z = f2bf(v.z); o.w = f2bf(v.w);
        *(ushort4v*)(nBT + off) = o;
        if (t == 0) nAdj[k] = emb_b[row] - NORM_TERM - lpn[row] - LOGK;
    } else {
        ushort4v z; z.x = 0; z.y = 0; z.z = 0; z.w = 0;
        *(ushort4v*)(nBT + off) = z;
        if (t == 0) nAdj[k] = 0.f;
    }
    if (k == 0 && t < 64) out[t] = 0.f;
}

// Block = 8 waves (512 thr) = 32 positions (two 16-row M-tiles).
// Staging: each wave stages 4 rows (full-row 2KB bursts input+target,
// fp32 target dot shfl-reduced to tdot[], input -> LDS bf16 swizzled).
// Barrier. Noise: wave w<7 owns k-tile w vs BOTH M-tiles (1KB B-bursts,
// 2 MFMAs each). Wave 7: 32 target epilogues. Tail: LDS blocksum +
// ONE atomicAdd per block into out[batch] (finalize kernel eliminated).
__global__ __launch_bounds__(512, 4) void nce_main(
    const float* __restrict__ input,     // [16384][512]
    const float* __restrict__ emb_w,     // [V][512]
    const float* __restrict__ emb_b,     // [V]
    const float* __restrict__ lpn,       // [V]
    const int* __restrict__ target,      // [16384]
    const unsigned short* __restrict__ nBT,  // noise, chunk-major bf16
    const float* __restrict__ nAdj,          // [112]
    float* __restrict__ out)                 // [64] accumulated
{
    __shared__ unsigned short A_lds[32 * 512];  // byte: row*1024 + (2c ^ ((row&7)<<4))
    __shared__ float tdot[32];
    __shared__ float blocksum[8];

    int tid  = threadIdx.x;
    int lane = tid & 63;
    int w    = tid >> 6;            // 0..7
    int pos0 = (int)blockIdx.x * 32;
    int r16  = lane & 15;
    int g4   = lane >> 4;

    // ---- Stage: 4 rows per wave; full-row 2KB bursts for input & target ----
#pragma unroll
    for (int j = 0; j < 4; ++j) {
        int row = w * 4 + j;                         // 0..31
        const float* src = input + (size_t)(pos0 + row) * Dq + lane * 8;
        int tg = target[pos0 + row];                 // wave-uniform -> scalar
        const float* tsrc = emb_w + (size_t)tg * Dq + lane * 8;
        floatx4 x0 = *(const floatx4*)(src);
        floatx4 x1 = *(const floatx4*)(src + 4);
        floatx4 t0 = *(const floatx4*)(tsrc);
        floatx4 t1 = *(const floatx4*)(tsrc + 4);
        float s = dot4(x0, t0) + dot4(x1, t1);
#pragma unroll
        for (int off = 32; off >= 1; off >>= 1)
            s += __shfl_xor(s, off);
        if (lane == 0) tdot[row] = s;
        char* base = (char*)A_lds + row * 1024;
        *(ushort8v*)(base + ((lane * 16) ^ ((row & 7) << 4))) = (ushort8v)cvt8(x0, x1);
    }
    __syncthreads();

    float contrib = 0.f;

    if (w < 7) {
        // ---- Noise k-tile w vs BOTH M-tiles: 1 B-burst -> 2 MFMAs ----
        const char* a0base = (const char*)A_lds + r16 * 1024;          // rows 0-15
        const char* a1base = a0base + 16 * 1024;                       // rows 16-31
        int asw = (r16 & 7) << 4;   // same swizzle for row and row+16
        const unsigned short* p = nBT + (size_t)w * 512 + r16 * 32 + g4 * 8;
        floatx4 acc0 = {0.f, 0.f, 0.f, 0.f};
        floatx4 acc1 = {0.f, 0.f, 0.f, 0.f};
#pragma unroll
        for (int dt = 0; dt < 16; ++dt) {
            int aoff = (dt * 64 + g4 * 16) ^ asw;
            short8 a0 = *(const short8*)(a0base + aoff);
            short8 a1 = *(const short8*)(a1base + aoff);
            short8 f  = *(const short8*)(p + (size_t)dt * DT_STRIDE);
            acc0 = __builtin_amdgcn_mfma_f32_16x16x32_bf16(a0, f, acc0, 0, 0, 0);
            acc1 = __builtin_amdgcn_mfma_f32_16x16x32_bf16(a1, f, acc1, 0, 0, 0);
        }
        int k = w * 16 + r16;
        if (k < Kq) {
            float adj = nAdj[k];
#pragma unroll
            for (int r = 0; r < 4; ++r) {
                contrib += log_sigmoid(-(acc0[r] + adj));
                contrib += log_sigmoid(-(acc1[r] + adj));
            }
        }
    } else {
        // ---- Target epilogue: lanes 0..31 own one position each ----
        if (g4 < 2) {
            int p32 = g4 * 16 + r16;                 // 0..31
            int tg = target[pos0 + p32];
            float xt = tdot[p32] + emb_b[tg] - NORM_TERM - lpn[tg] - LOGK;
            contrib += log_sigmoid(xt);
        }
    }

#pragma unroll
    for (int off = 32; off >= 1; off >>= 1)
        contrib += __shfl_xor(contrib, off);
    if (lane == 0) blocksum[w] = contrib;
    __syncthreads();

    // ---- One atomic per block (8 per out address, 512 total) ----
    if (tid == 0) {
        float s = 0.f;
#pragma unroll
        for (int i = 0; i < 8; ++i) s += blocksum[i];
        atomicAdd(&out[blockIdx.x >> 3], s);         // batch = pos0/256
    }
}

extern "C" void kernel_launch(void* const* d_in, const int* in_sizes, int n_in,
                              void* d_out, int out_size, void* d_ws, size_t ws_size,
                              hipStream_t stream) {
    const float* input = (const float*)d_in[0];
    const float* emb_w = (const float*)d_in[1];
    const float* emb_b = (const float*)d_in[2];
    const float* lpn   = (const float*)d_in[3];
    const int*   tgt   = (const int*)d_in[4];
    const int*   ns    = (const int*)d_in[5];
    float* out = (float*)d_out;

    // ws layout: [0,114688) nBT bf16; [114688,115200) nAdj(+pad).
    unsigned short* nBT = (unsigned short*)d_ws;
    float* nAdj         = (float*)((char*)d_ws + (size_t)KP * Dq * 2);

    prep_noise<<<KP, 128, 0, stream>>>(emb_w, emb_b, lpn, ns, nBT, nAdj, out);
    nce_main<<<NBLK, 512, 0, stream>>>(input, emb_w, emb_b, lpn, tgt,
                                       nBT, nAdj, out);
}